// Round 1
// baseline (456.486 us; speedup 1.0000x reference)
//
#include <hip/hip_runtime.h>

// Problem: B=2048, C=16, S=2000, fp32.
// Reference collapses: softmax rows sum to 1, so the attention branch
// multiplies x by 1.0 (±1e-7). out = LN_c(Wp @ x[b,:,s] + bp)*gp + hp.
// Memory-bound: 262 MB in + 262 MB out -> ~83 us roofline @ 6.3 TB/s.

#define NC 16          // channels
#define NS 2000        // sequence
#define SV (NS / 4)    // 500 float4 per (b,c) row
#define EPS 1e-5f
#define BLK 256

__global__ __launch_bounds__(BLK) void chanattn_fused(
    const float* __restrict__ x,
    const float* __restrict__ Wp,
    const float* __restrict__ bp,
    const float* __restrict__ gp,
    const float* __restrict__ hp,
    float* __restrict__ out,
    unsigned total)        // B * SV
{
    // Stage params in LDS. sW[cp][c] = Wp[c][cp] (transposed) so the
    // accumulation loop reads a contiguous row per input channel; all lanes
    // read the same address -> LDS broadcast, no bank conflicts.
    __shared__ float sW[NC * NC];
    __shared__ float sb[NC], sg[NC], sh[NC];
    const int tid = threadIdx.x;
    if (tid < NC * NC) sW[(tid & (NC - 1)) * NC + (tid >> 4)] = Wp[tid];
    if (tid < NC) { sb[tid] = bp[tid]; sg[tid] = gp[tid]; sh[tid] = hp[tid]; }
    __syncthreads();

    const unsigned t = blockIdx.x * BLK + tid;
    if (t >= total) return;
    const unsigned b  = t / SV;        // const-division -> magic mul
    const unsigned s4 = t - b * SV;

    const float4* __restrict__ px = (const float4*)x   + (size_t)b * (NC * SV) + s4;
    float4*       __restrict__ po = (float4*)out       + (size_t)b * (NC * SV) + s4;

    // Load all 16 channel float4s up front: 16 independent loads in flight
    // per wave (1 KiB/instruction across 64 lanes, perfectly coalesced).
    float4 xv[NC];
#pragma unroll
    for (int c = 0; c < NC; ++c) xv[c] = px[c * SV];

    // y[c] = bp[c] + sum_cp Wp[c][cp] * x[cp]   (4 positions at once)
    float4 y[NC];
#pragma unroll
    for (int c = 0; c < NC; ++c) {
        const float bb = sb[c];
        y[c].x = bb; y[c].y = bb; y[c].z = bb; y[c].w = bb;
    }
#pragma unroll
    for (int cp = 0; cp < NC; ++cp) {
        const float4 xc = xv[cp];
#pragma unroll
        for (int c = 0; c < NC; ++c) {
            const float w = sW[cp * NC + c];
            y[c].x = fmaf(w, xc.x, y[c].x);
            y[c].y = fmaf(w, xc.y, y[c].y);
            y[c].z = fmaf(w, xc.z, y[c].z);
            y[c].w = fmaf(w, xc.w, y[c].w);
        }
    }

    // LayerNorm over the 16 channels, per position (two-pass, in registers).
    float4 sum; sum.x = sum.y = sum.z = sum.w = 0.f;
#pragma unroll
    for (int c = 0; c < NC; ++c) {
        sum.x += y[c].x; sum.y += y[c].y; sum.z += y[c].z; sum.w += y[c].w;
    }
    const float inv = 1.0f / NC;
    float4 mu;
    mu.x = sum.x * inv; mu.y = sum.y * inv; mu.z = sum.z * inv; mu.w = sum.w * inv;

    float4 var; var.x = var.y = var.z = var.w = 0.f;
#pragma unroll
    for (int c = 0; c < NC; ++c) {
        float dx = y[c].x - mu.x, dy = y[c].y - mu.y,
              dz = y[c].z - mu.z, dw = y[c].w - mu.w;
        var.x = fmaf(dx, dx, var.x);
        var.y = fmaf(dy, dy, var.y);
        var.z = fmaf(dz, dz, var.z);
        var.w = fmaf(dw, dw, var.w);
    }
    float4 r;
    r.x = rsqrtf(var.x * inv + EPS);
    r.y = rsqrtf(var.y * inv + EPS);
    r.z = rsqrtf(var.z * inv + EPS);
    r.w = rsqrtf(var.w * inv + EPS);

#pragma unroll
    for (int c = 0; c < NC; ++c) {
        const float g = sg[c], h = sh[c];
        float4 o;
        o.x = fmaf((y[c].x - mu.x) * r.x, g, h);
        o.y = fmaf((y[c].y - mu.y) * r.y, g, h);
        o.z = fmaf((y[c].z - mu.z) * r.z, g, h);
        o.w = fmaf((y[c].w - mu.w) * r.w, g, h);
        po[c * SV] = o;
    }
}

extern "C" void kernel_launch(void* const* d_in, const int* in_sizes, int n_in,
                              void* d_out, int out_size, void* d_ws, size_t ws_size,
                              hipStream_t stream) {
    // setup_inputs order: x, Wq, bq, gq, hq, Wk, bk, gk, hk, Wp, bp, gp, hp
    const float* x  = (const float*)d_in[0];
    const float* Wp = (const float*)d_in[9];
    const float* bp = (const float*)d_in[10];
    const float* gp = (const float*)d_in[11];
    const float* hp = (const float*)d_in[12];
    float* out = (float*)d_out;

    const unsigned B = (unsigned)(in_sizes[0] / (NC * NS));  // 2048
    const unsigned total = B * SV;                            // 1,024,000
    const unsigned grid = (total + BLK - 1) / BLK;            // 4000
    chanattn_fused<<<grid, BLK, 0, stream>>>(x, Wp, bp, gp, hp, out, total);
}